// Round 1
// baseline (1223.314 us; speedup 1.0000x reference)
//
#include <hip/hip_runtime.h>
#include <math.h>

#define H 64
#define FIN 39

// ---- count in-degree: cnt[col[e]] += 1 ----
__global__ void k_count(const int* __restrict__ col, float* __restrict__ cnt, int E) {
    int e = blockIdx.x * 256 + threadIdx.x;
    if (e < E) atomicAdd(&cnt[col[e]], 1.0f);
}

// ---- h = x @ W_in + b_in ----
__global__ void k_input(const float* __restrict__ x, const float* __restrict__ Win,
                        const float* __restrict__ bin, float* __restrict__ h, int N) {
    __shared__ float w[FIN * H];
    __shared__ float b[H];
    __shared__ float xs[4][FIN];
    int tid = threadIdx.x;
    for (int i = tid; i < FIN * H; i += 256) w[i] = Win[i];
    if (tid < H) b[tid] = bin[tid];
    int ln = tid >> 6, j = tid & 63;
    int n = blockIdx.x * 4 + ln;
    if (n < N && j < FIN) xs[ln][j] = x[n * FIN + j];
    __syncthreads();
    if (n >= N) return;
    float acc = b[j];
    #pragma unroll
    for (int k = 0; k < FIN; ++k) acc += xs[ln][k] * w[k * H + j];
    h[n * H + j] = acc;
}

// ---- A = h @ W_top ; aggr = cnt * (h @ W_bot + msg_b) ----
__global__ void k_AB(const float* __restrict__ h, const float* __restrict__ W,
                     const float* __restrict__ bias, const float* __restrict__ cnt,
                     float* __restrict__ A, float* __restrict__ aggr, int N) {
    __shared__ float w[2 * H * H];
    __shared__ float bs[H];
    __shared__ float hs[4][H];
    int tid = threadIdx.x;
    for (int i = tid; i < 2 * H * H; i += 256) w[i] = W[i];
    if (tid < H) bs[tid] = bias[tid];
    int ln = tid >> 6, j = tid & 63;
    int n = blockIdx.x * 4 + ln;
    if (n < N) hs[ln][j] = h[n * H + j];
    __syncthreads();
    if (n >= N) return;
    float a = 0.f, bacc = 0.f;
    #pragma unroll
    for (int k = 0; k < H; ++k) {
        float hk = hs[ln][k];
        a    += hk * w[k * H + j];
        bacc += hk * w[(H + k) * H + j];
    }
    A[n * H + j] = a;
    float c = cnt[n];
    aggr[n * H + j] = c * (bacc + bs[j]);
}

// ---- aggr[col[e]][:] += A[row[e]][:]  (64 lanes = 1 edge) ----
__global__ void k_edges(const int* __restrict__ row, const int* __restrict__ col,
                        const float* __restrict__ A, float* __restrict__ aggr, int E) {
    int t = blockIdx.x * 256 + threadIdx.x;
    int e = t >> 6, j = t & 63;
    if (e < E) {
        int r = row[e], c = col[e];
        atomicAdd(&aggr[c * H + j], A[r * H + j]);
    }
}

// ---- upd = [h, aggr/denom] @ upd_W + b ; h = LN(h + upd) * g + beta ----
__global__ void k_upd(float* __restrict__ h, const float* __restrict__ aggr,
                      const float* __restrict__ cnt, const float* __restrict__ W,
                      const float* __restrict__ bias, const float* __restrict__ g,
                      const float* __restrict__ beta, int N) {
    __shared__ float w[2 * H * H];
    __shared__ float bs[H], gs[H], betas[H];
    __shared__ float hs[4][H], as[4][H];
    int tid = threadIdx.x;
    for (int i = tid; i < 2 * H * H; i += 256) w[i] = W[i];
    if (tid < H) { bs[tid] = bias[tid]; gs[tid] = g[tid]; betas[tid] = beta[tid]; }
    int ln = tid >> 6, j = tid & 63;
    int n = blockIdx.x * 4 + ln;
    float hv = 0.f;
    if (n < N) {
        float c = cnt[n];
        float denom = fmaxf(c, 1.0f);
        hv = h[n * H + j];
        hs[ln][j] = hv;
        as[ln][j] = aggr[n * H + j] / denom;
    }
    __syncthreads();
    if (n >= N) return;
    float acc = bs[j];
    #pragma unroll
    for (int k = 0; k < H; ++k) {
        acc += hs[ln][k] * w[k * H + j] + as[ln][k] * w[(H + k) * H + j];
    }
    float z = hv + acc;
    // LayerNorm across the 64 lanes of this wave (one node per wave)
    float s = z;
    for (int o = 32; o > 0; o >>= 1) s += __shfl_xor(s, o);
    float mu = s * (1.0f / H);
    float d = z - mu;
    float v = d * d;
    for (int o = 32; o > 0; o >>= 1) v += __shfl_xor(v, o);
    float var = v * (1.0f / H);
    float r = rsqrtf(var + 1e-5f);
    h[n * H + j] = d * r * gs[j] + betas[j];
}

// ---- out = sigmoid(gelu(h @ W1 + b1) @ W2 + b2) ----
__global__ void k_out(const float* __restrict__ h, const float* __restrict__ W1,
                      const float* __restrict__ b1, const float* __restrict__ W2,
                      const float* __restrict__ b2, float* __restrict__ out, int N) {
    __shared__ float w1[H * 32];
    __shared__ float w2[32];
    __shared__ float b1s[32];
    __shared__ float hs[4][H];
    int tid = threadIdx.x;
    for (int i = tid; i < H * 32; i += 256) w1[i] = W1[i];
    if (tid < 32) { w2[tid] = W2[tid]; b1s[tid] = b1[tid]; }
    int ln = tid >> 6, j = tid & 63;
    int n = blockIdx.x * 4 + ln;
    if (n < N) hs[ln][j] = h[n * H + j];
    __syncthreads();
    if (n >= N) return;
    float ge = 0.f;
    if (j < 32) {
        float t = b1s[j];
        #pragma unroll
        for (int k = 0; k < H; ++k) t += hs[ln][k] * w1[k * 32 + j];
        ge = 0.5f * t * (1.0f + erff(t * 0.70710678118654752f)) * w2[j];
    }
    float s = ge;
    for (int o = 32; o > 0; o >>= 1) s += __shfl_xor(s, o);
    if (j == 0) out[n] = 1.0f / (1.0f + expf(-(s + b2[0])));
}

extern "C" void kernel_launch(void* const* d_in, const int* in_sizes, int n_in,
                              void* d_out, int out_size, void* d_ws, size_t ws_size,
                              hipStream_t stream) {
    const float* x    = (const float*)d_in[0];
    const int*   ei   = (const int*)d_in[1];
    const float* Win  = (const float*)d_in[2];
    const float* bin  = (const float*)d_in[3];
    const float* msgW = (const float*)d_in[4];
    const float* msgb = (const float*)d_in[5];
    const float* updW = (const float*)d_in[6];
    const float* updb = (const float*)d_in[7];
    const float* lng  = (const float*)d_in[8];
    const float* lnb  = (const float*)d_in[9];
    const float* W1   = (const float*)d_in[10];
    const float* b1   = (const float*)d_in[11];
    const float* W2   = (const float*)d_in[12];
    const float* b2   = (const float*)d_in[13];

    int N = in_sizes[0] / FIN;
    int E = in_sizes[1] / 2;
    const int* row = ei;
    const int* col = ei + E;

    float* ws  = (float*)d_ws;
    float* cnt = ws;                       // N
    float* h   = ws + N;                   // N*H
    float* A   = h + (size_t)N * H;        // N*H
    float* ag  = A + (size_t)N * H;        // N*H

    hipMemsetAsync(cnt, 0, (size_t)N * sizeof(float), stream);
    k_count<<<(E + 255) / 256, 256, 0, stream>>>(col, cnt, E);
    k_input<<<(N + 3) / 4, 256, 0, stream>>>(x, Win, bin, h, N);

    for (int l = 0; l < 2; ++l) {
        k_AB<<<(N + 3) / 4, 256, 0, stream>>>(h, msgW + (size_t)l * 2 * H * H,
                                              msgb + (size_t)l * H, cnt, A, ag, N);
        k_edges<<<(E + 3) / 4, 256, 0, stream>>>(row, col, A, ag, E);
        k_upd<<<(N + 3) / 4, 256, 0, stream>>>(h, ag, cnt, updW + (size_t)l * 2 * H * H,
                                               updb + (size_t)l * H, lng + (size_t)l * H,
                                               lnb + (size_t)l * H, N);
    }
    k_out<<<(N + 3) / 4, 256, 0, stream>>>(h, W1, b1, W2, b2, (float*)d_out, N);
}

// Round 2
// 799.322 us; speedup vs baseline: 1.5304x; 1.5304x over previous
//
#include <hip/hip_runtime.h>
#include <math.h>

#define H 64
#define FIN 39

// ---- in-degree (int) ----
__global__ void k_deg(const int* __restrict__ col, int* __restrict__ deg, int E) {
    int e = blockIdx.x * 256 + threadIdx.x;
    if (e < E) atomicAdd(&deg[col[e]], 1);
}

// ---- scan step 1: per-block exclusive scan of deg; block sums out; also float cnt ----
__global__ void k_scan1(const int* __restrict__ deg, int* __restrict__ startv,
                        int* __restrict__ bsum, float* __restrict__ cnt, int N) {
    __shared__ int lds[256];
    int tid = threadIdx.x;
    int i = blockIdx.x * 256 + tid;
    int v = (i < N) ? deg[i] : 0;
    if (i < N) cnt[i] = (float)v;
    lds[tid] = v;
    __syncthreads();
    int acc = v;
    for (int off = 1; off < 256; off <<= 1) {
        int t = (tid >= off) ? lds[tid - off] : 0;
        __syncthreads();
        acc += t;
        lds[tid] = acc;
        __syncthreads();
    }
    if (i < N) startv[i] = acc - v;           // exclusive within block
    if (tid == 255) bsum[blockIdx.x] = acc;   // block total
}

// ---- scan step 2: exclusive scan of block sums (nb <= 512) ----
__global__ void k_scan2(int* __restrict__ bsum, int nb) {
    __shared__ int lds[512];
    int tid = threadIdx.x;
    int v = (tid < nb) ? bsum[tid] : 0;
    lds[tid] = v;
    __syncthreads();
    int acc = v;
    for (int off = 1; off < 512; off <<= 1) {
        int t = (tid >= off) ? lds[tid - off] : 0;
        __syncthreads();
        acc += t;
        lds[tid] = acc;
        __syncthreads();
    }
    if (tid < nb) bsum[tid] = acc - v;
}

// ---- scan step 3: add block offsets; init cursor ----
__global__ void k_scan3(int* __restrict__ startv, const int* __restrict__ bsum,
                        int* __restrict__ cursor, int N) {
    int i = blockIdx.x * 256 + threadIdx.x;
    if (i < N) {
        int s = startv[i] + bsum[blockIdx.x];
        startv[i] = s;
        cursor[i] = s;
    }
}

// ---- fill CSR: csr[pos] = row[e], bucketed by col[e] ----
__global__ void k_fill(const int* __restrict__ row, const int* __restrict__ col,
                       int* __restrict__ cursor, int* __restrict__ csr, int E) {
    int e = blockIdx.x * 256 + threadIdx.x;
    if (e < E) {
        int c = col[e];
        int pos = atomicAdd(&cursor[c], 1);
        csr[pos] = row[e];
    }
}

// ---- h = x @ W_in + b_in ----
__global__ void k_input(const float* __restrict__ x, const float* __restrict__ Win,
                        const float* __restrict__ bin, float* __restrict__ h, int N) {
    __shared__ float w[FIN * H];
    __shared__ float b[H];
    __shared__ float xs[4][FIN];
    int tid = threadIdx.x;
    for (int i = tid; i < FIN * H; i += 256) w[i] = Win[i];
    if (tid < H) b[tid] = bin[tid];
    int ln = tid >> 6, j = tid & 63;
    int n = blockIdx.x * 4 + ln;
    if (n < N && j < FIN) xs[ln][j] = x[n * FIN + j];
    __syncthreads();
    if (n >= N) return;
    float acc = b[j];
    #pragma unroll
    for (int k = 0; k < FIN; ++k) acc += xs[ln][k] * w[k * H + j];
    h[n * H + j] = acc;
}

// ---- A = h @ W_top ; aggr_init = cnt * (h @ W_bot + msg_b) ----
__global__ void k_AB(const float* __restrict__ h, const float* __restrict__ W,
                     const float* __restrict__ bias, const float* __restrict__ cnt,
                     float* __restrict__ A, float* __restrict__ aggr, int N) {
    __shared__ float w[2 * H * H];
    __shared__ float bs[H];
    __shared__ float hs[4][H];
    int tid = threadIdx.x;
    for (int i = tid; i < 2 * H * H; i += 256) w[i] = W[i];
    if (tid < H) bs[tid] = bias[tid];
    int ln = tid >> 6, j = tid & 63;
    int n = blockIdx.x * 4 + ln;
    if (n < N) hs[ln][j] = h[n * H + j];
    __syncthreads();
    if (n >= N) return;
    float a = 0.f, bacc = 0.f;
    #pragma unroll
    for (int k = 0; k < H; ++k) {
        float hk = hs[ln][k];
        a    += hk * w[k * H + j];
        bacc += hk * w[(H + k) * H + j];
    }
    A[n * H + j] = a;
    float c = cnt[n];
    aggr[n * H + j] = c * (bacc + bs[j]);
}

// ---- aggr[n][:] += sum over incoming edges of A[src][:]  (CSR gather, no atomics) ----
__global__ void k_aggr(const int* __restrict__ startv, const int* __restrict__ deg,
                       const int* __restrict__ csr, const float* __restrict__ A,
                       float* __restrict__ ag, int N) {
    int tid = threadIdx.x;
    int n = blockIdx.x * 4 + (tid >> 6);
    int j = tid & 63;
    if (n >= N) return;
    int s = startv[n];
    int d = deg[n];
    float acc = ag[n * H + j];
    int i = 0;
    for (; i + 4 <= d; i += 4) {
        int r0 = csr[s + i], r1 = csr[s + i + 1], r2 = csr[s + i + 2], r3 = csr[s + i + 3];
        float v0 = A[r0 * H + j];
        float v1 = A[r1 * H + j];
        float v2 = A[r2 * H + j];
        float v3 = A[r3 * H + j];
        acc += v0 + v1 + v2 + v3;
    }
    for (; i < d; ++i) {
        int r = csr[s + i];
        acc += A[r * H + j];
    }
    ag[n * H + j] = acc;
}

// ---- upd = [h, aggr/denom] @ upd_W + b ; h = LN(h + upd) * g + beta ----
__global__ void k_upd(float* __restrict__ h, const float* __restrict__ aggr,
                      const float* __restrict__ cnt, const float* __restrict__ W,
                      const float* __restrict__ bias, const float* __restrict__ g,
                      const float* __restrict__ beta, int N) {
    __shared__ float w[2 * H * H];
    __shared__ float bs[H], gs[H], betas[H];
    __shared__ float hs[4][H], as[4][H];
    int tid = threadIdx.x;
    for (int i = tid; i < 2 * H * H; i += 256) w[i] = W[i];
    if (tid < H) { bs[tid] = bias[tid]; gs[tid] = g[tid]; betas[tid] = beta[tid]; }
    int ln = tid >> 6, j = tid & 63;
    int n = blockIdx.x * 4 + ln;
    float hv = 0.f;
    if (n < N) {
        float c = cnt[n];
        float denom = fmaxf(c, 1.0f);
        hv = h[n * H + j];
        hs[ln][j] = hv;
        as[ln][j] = aggr[n * H + j] / denom;
    }
    __syncthreads();
    if (n >= N) return;
    float acc = bs[j];
    #pragma unroll
    for (int k = 0; k < H; ++k) {
        acc += hs[ln][k] * w[k * H + j] + as[ln][k] * w[(H + k) * H + j];
    }
    float z = hv + acc;
    float s = z;
    for (int o = 32; o > 0; o >>= 1) s += __shfl_xor(s, o);
    float mu = s * (1.0f / H);
    float d = z - mu;
    float v = d * d;
    for (int o = 32; o > 0; o >>= 1) v += __shfl_xor(v, o);
    float var = v * (1.0f / H);
    float r = rsqrtf(var + 1e-5f);
    h[n * H + j] = d * r * gs[j] + betas[j];
}

// ---- out = sigmoid(gelu(h @ W1 + b1) @ W2 + b2) ----
__global__ void k_out(const float* __restrict__ h, const float* __restrict__ W1,
                      const float* __restrict__ b1, const float* __restrict__ W2,
                      const float* __restrict__ b2, float* __restrict__ out, int N) {
    __shared__ float w1[H * 32];
    __shared__ float w2[32];
    __shared__ float b1s[32];
    __shared__ float hs[4][H];
    int tid = threadIdx.x;
    for (int i = tid; i < H * 32; i += 256) w1[i] = W1[i];
    if (tid < 32) { w2[tid] = W2[tid]; b1s[tid] = b1[tid]; }
    int ln = tid >> 6, j = tid & 63;
    int n = blockIdx.x * 4 + ln;
    if (n < N) hs[ln][j] = h[n * H + j];
    __syncthreads();
    if (n >= N) return;
    float ge = 0.f;
    if (j < 32) {
        float t = b1s[j];
        #pragma unroll
        for (int k = 0; k < H; ++k) t += hs[ln][k] * w1[k * 32 + j];
        ge = 0.5f * t * (1.0f + erff(t * 0.70710678118654752f)) * w2[j];
    }
    float s = ge;
    for (int o = 32; o > 0; o >>= 1) s += __shfl_xor(s, o);
    if (j == 0) out[n] = 1.0f / (1.0f + expf(-(s + b2[0])));
}

extern "C" void kernel_launch(void* const* d_in, const int* in_sizes, int n_in,
                              void* d_out, int out_size, void* d_ws, size_t ws_size,
                              hipStream_t stream) {
    const float* x    = (const float*)d_in[0];
    const int*   ei   = (const int*)d_in[1];
    const float* Win  = (const float*)d_in[2];
    const float* bin  = (const float*)d_in[3];
    const float* msgW = (const float*)d_in[4];
    const float* msgb = (const float*)d_in[5];
    const float* updW = (const float*)d_in[6];
    const float* updb = (const float*)d_in[7];
    const float* lng  = (const float*)d_in[8];
    const float* lnb  = (const float*)d_in[9];
    const float* W1   = (const float*)d_in[10];
    const float* b1   = (const float*)d_in[11];
    const float* W2   = (const float*)d_in[12];
    const float* b2   = (const float*)d_in[13];

    int N = in_sizes[0] / FIN;
    int E = in_sizes[1] / 2;
    const int* row = ei;
    const int* col = ei + E;

    float* ws   = (float*)d_ws;
    float* cnt  = ws;                        // N
    float* h    = ws + N;                    // N*H
    float* A    = h + (size_t)N * H;         // N*H
    float* ag   = A + (size_t)N * H;         // N*H
    int* deg    = (int*)(ag + (size_t)N * H);// N
    int* startv = deg + N;                   // N
    int* cursor = startv + N;                // N
    int* bsum   = cursor + N;                // 512
    int* csr    = bsum + 512;                // E

    int nb = (N + 255) / 256;

    hipMemsetAsync(deg, 0, (size_t)N * sizeof(int), stream);
    k_deg<<<(E + 255) / 256, 256, 0, stream>>>(col, deg, E);
    k_scan1<<<nb, 256, 0, stream>>>(deg, startv, bsum, cnt, N);
    k_scan2<<<1, 512, 0, stream>>>(bsum, nb);
    k_scan3<<<nb, 256, 0, stream>>>(startv, bsum, cursor, N);
    k_fill<<<(E + 255) / 256, 256, 0, stream>>>(row, col, cursor, csr, E);

    k_input<<<(N + 3) / 4, 256, 0, stream>>>(x, Win, bin, h, N);

    for (int l = 0; l < 2; ++l) {
        k_AB<<<(N + 3) / 4, 256, 0, stream>>>(h, msgW + (size_t)l * 2 * H * H,
                                              msgb + (size_t)l * H, cnt, A, ag, N);
        k_aggr<<<(N + 3) / 4, 256, 0, stream>>>(startv, deg, csr, A, ag, N);
        k_upd<<<(N + 3) / 4, 256, 0, stream>>>(h, ag, cnt, updW + (size_t)l * 2 * H * H,
                                               updb + (size_t)l * H, lng + (size_t)l * H,
                                               lnb + (size_t)l * H, N);
    }
    k_out<<<(N + 3) / 4, 256, 0, stream>>>(h, W1, b1, W2, b2, (float*)d_out, N);
}

// Round 3
// 662.565 us; speedup vs baseline: 1.8463x; 1.2064x over previous
//
#include <hip/hip_runtime.h>
#include <math.h>

#define H 64
#define FIN 39

// ---- in-degree (int) ----
__global__ void k_deg(const int* __restrict__ col, int* __restrict__ deg, int E) {
    int e = blockIdx.x * 256 + threadIdx.x;
    if (e < E) atomicAdd(&deg[col[e]], 1);
}

// ---- scan step 1: per-block exclusive scan of deg; block sums out; also float cnt ----
__global__ void k_scan1(const int* __restrict__ deg, int* __restrict__ startv,
                        int* __restrict__ bsum, float* __restrict__ cnt, int N) {
    __shared__ int lds[256];
    int tid = threadIdx.x;
    int i = blockIdx.x * 256 + tid;
    int v = (i < N) ? deg[i] : 0;
    if (i < N) cnt[i] = (float)v;
    lds[tid] = v;
    __syncthreads();
    int acc = v;
    for (int off = 1; off < 256; off <<= 1) {
        int t = (tid >= off) ? lds[tid - off] : 0;
        __syncthreads();
        acc += t;
        lds[tid] = acc;
        __syncthreads();
    }
    if (i < N) startv[i] = acc - v;
    if (tid == 255) bsum[blockIdx.x] = acc;
}

// ---- scan step 2: exclusive scan of block sums (nb <= 512) ----
__global__ void k_scan2(int* __restrict__ bsum, int nb) {
    __shared__ int lds[512];
    int tid = threadIdx.x;
    int v = (tid < nb) ? bsum[tid] : 0;
    lds[tid] = v;
    __syncthreads();
    int acc = v;
    for (int off = 1; off < 512; off <<= 1) {
        int t = (tid >= off) ? lds[tid - off] : 0;
        __syncthreads();
        acc += t;
        lds[tid] = acc;
        __syncthreads();
    }
    if (tid < nb) bsum[tid] = acc - v;
}

// ---- scan step 3: add block offsets; init cursor ----
__global__ void k_scan3(int* __restrict__ startv, const int* __restrict__ bsum,
                        int* __restrict__ cursor, int N) {
    int i = blockIdx.x * 256 + threadIdx.x;
    if (i < N) {
        int s = startv[i] + bsum[blockIdx.x];
        startv[i] = s;
        cursor[i] = s;
    }
}

// ---- fill CSR: csr[pos] = row[e], bucketed by col[e] ----
__global__ void k_fill(const int* __restrict__ row, const int* __restrict__ col,
                       int* __restrict__ cursor, int* __restrict__ csr, int E) {
    int e = blockIdx.x * 256 + threadIdx.x;
    if (e < E) {
        int c = col[e];
        int pos = atomicAdd(&cursor[c], 1);
        csr[pos] = row[e];
    }
}

// ---- h = x @ W_in + b_in : 16 nodes/block, 4 nodes/thread, scalar x reads ----
__global__ void k_input(const float* __restrict__ x, const float* __restrict__ Win,
                        const float* __restrict__ bin, float* __restrict__ h, int N) {
    __shared__ float w[FIN * H];
    int tid = threadIdx.x;
    for (int i = tid; i < FIN * H; i += 256) w[i] = Win[i];
    __syncthreads();
    int j = tid & 63;
    int nb0 = blockIdx.x * 16 + (tid >> 6) * 4;
    int un = __builtin_amdgcn_readfirstlane(nb0);
    int n0 = min(un, N - 1), n1 = min(un + 1, N - 1), n2 = min(un + 2, N - 1), n3 = min(un + 3, N - 1);
    const float* x0 = x + (size_t)n0 * FIN;
    const float* x1 = x + (size_t)n1 * FIN;
    const float* x2 = x + (size_t)n2 * FIN;
    const float* x3 = x + (size_t)n3 * FIN;
    float a0 = 0.f, a1 = 0.f, a2 = 0.f, a3 = 0.f;
    #pragma unroll
    for (int k = 0; k < FIN; ++k) {
        float wv = w[k * H + j];
        a0 += x0[k] * wv;
        a1 += x1[k] * wv;
        a2 += x2[k] * wv;
        a3 += x3[k] * wv;
    }
    float bj = bin[j];
    if (un     < N) h[(size_t)n0 * H + j] = a0 + bj;
    if (un + 1 < N) h[(size_t)n1 * H + j] = a1 + bj;
    if (un + 2 < N) h[(size_t)n2 * H + j] = a2 + bj;
    if (un + 3 < N) h[(size_t)n3 * H + j] = a3 + bj;
}

// ---- A = h @ W_top ; aggr_init = cnt * (h @ W_bot + msg_b) ----
// 16 nodes/block, 4 nodes/thread; h rows read via wave-uniform scalar loads.
__global__ void k_AB(const float* __restrict__ h, const float* __restrict__ W,
                     const float* __restrict__ bias, const float* __restrict__ cnt,
                     float* __restrict__ A, float* __restrict__ aggr, int N) {
    __shared__ float ws[2 * H * H];
    int tid = threadIdx.x;
    {
        const float4* W4 = (const float4*)W;
        float4* s4 = (float4*)ws;
        for (int i = tid; i < 2 * H * H / 4; i += 256) s4[i] = W4[i];
    }
    __syncthreads();
    int j = tid & 63;
    int nb0 = blockIdx.x * 16 + (tid >> 6) * 4;
    int un = __builtin_amdgcn_readfirstlane(nb0);
    int n0 = min(un, N - 1), n1 = min(un + 1, N - 1), n2 = min(un + 2, N - 1), n3 = min(un + 3, N - 1);
    const float* h0 = h + (size_t)n0 * H;
    const float* h1 = h + (size_t)n1 * H;
    const float* h2 = h + (size_t)n2 * H;
    const float* h3 = h + (size_t)n3 * H;
    float a0 = 0.f, a1 = 0.f, a2 = 0.f, a3 = 0.f;
    float b0 = 0.f, b1 = 0.f, b2 = 0.f, b3 = 0.f;
    #pragma unroll 8
    for (int k = 0; k < H; ++k) {
        float w0 = ws[k * H + j];
        float w1 = ws[(H + k) * H + j];
        float s0 = h0[k], s1 = h1[k], s2 = h2[k], s3 = h3[k];
        a0 += s0 * w0; b0 += s0 * w1;
        a1 += s1 * w0; b1 += s1 * w1;
        a2 += s2 * w0; b2 += s2 * w1;
        a3 += s3 * w0; b3 += s3 * w1;
    }
    float bj = bias[j];
    if (un < N) {
        float c = cnt[n0];
        A[(size_t)n0 * H + j] = a0;
        aggr[(size_t)n0 * H + j] = c * (b0 + bj);
    }
    if (un + 1 < N) {
        float c = cnt[n1];
        A[(size_t)n1 * H + j] = a1;
        aggr[(size_t)n1 * H + j] = c * (b1 + bj);
    }
    if (un + 2 < N) {
        float c = cnt[n2];
        A[(size_t)n2 * H + j] = a2;
        aggr[(size_t)n2 * H + j] = c * (b2 + bj);
    }
    if (un + 3 < N) {
        float c = cnt[n3];
        A[(size_t)n3 * H + j] = a3;
        aggr[(size_t)n3 * H + j] = c * (b3 + bj);
    }
}

// ---- aggr[n][:] += sum over incoming edges of A[src][:]  (CSR gather, no atomics) ----
__global__ void k_aggr(const int* __restrict__ startv, const int* __restrict__ deg,
                       const int* __restrict__ csr, const float* __restrict__ A,
                       float* __restrict__ ag, int N) {
    int tid = threadIdx.x;
    int n = blockIdx.x * 4 + (tid >> 6);
    int j = tid & 63;
    if (n >= N) return;
    int s = startv[n];
    int d = deg[n];
    float acc = ag[n * H + j];
    int i = 0;
    for (; i + 4 <= d; i += 4) {
        int r0 = csr[s + i], r1 = csr[s + i + 1], r2 = csr[s + i + 2], r3 = csr[s + i + 3];
        float v0 = A[r0 * H + j];
        float v1 = A[r1 * H + j];
        float v2 = A[r2 * H + j];
        float v3 = A[r3 * H + j];
        acc += v0 + v1 + v2 + v3;
    }
    for (; i < d; ++i) {
        int r = csr[s + i];
        acc += A[r * H + j];
    }
    ag[n * H + j] = acc;
}

// ---- upd = [h, aggr/denom] @ upd_W + b ; hout = LN(h + upd) * g + beta ----
// 16 nodes/block, 4 nodes/thread; h/aggr rows via wave-uniform scalar loads.
__global__ void k_upd(const float* __restrict__ hin, const float* __restrict__ ag,
                      const float* __restrict__ cnt, const float* __restrict__ W,
                      const float* __restrict__ bias, const float* __restrict__ g,
                      const float* __restrict__ beta, float* __restrict__ hout, int N) {
    __shared__ float ws[2 * H * H];
    int tid = threadIdx.x;
    {
        const float4* W4 = (const float4*)W;
        float4* s4 = (float4*)ws;
        for (int i = tid; i < 2 * H * H / 4; i += 256) s4[i] = W4[i];
    }
    __syncthreads();
    int j = tid & 63;
    int nb0 = blockIdx.x * 16 + (tid >> 6) * 4;
    int un = __builtin_amdgcn_readfirstlane(nb0);
    int n0 = min(un, N - 1), n1 = min(un + 1, N - 1), n2 = min(un + 2, N - 1), n3 = min(un + 3, N - 1);
    const float* h0 = hin + (size_t)n0 * H;
    const float* h1 = hin + (size_t)n1 * H;
    const float* h2 = hin + (size_t)n2 * H;
    const float* h3 = hin + (size_t)n3 * H;
    const float* g0 = ag + (size_t)n0 * H;
    const float* g1 = ag + (size_t)n1 * H;
    const float* g2 = ag + (size_t)n2 * H;
    const float* g3 = ag + (size_t)n3 * H;
    float uH0 = 0.f, uH1 = 0.f, uH2 = 0.f, uH3 = 0.f;
    float uA0 = 0.f, uA1 = 0.f, uA2 = 0.f, uA3 = 0.f;
    #pragma unroll 4
    for (int k = 0; k < H; ++k) {
        float w0 = ws[k * H + j];
        float w1 = ws[(H + k) * H + j];
        uH0 += h0[k] * w0; uA0 += g0[k] * w1;
        uH1 += h1[k] * w0; uA1 += g1[k] * w1;
        uH2 += h2[k] * w0; uA2 += g2[k] * w1;
        uH3 += h3[k] * w0; uA3 += g3[k] * w1;
    }
    float bj = bias[j], gj = g[j], betaj = beta[j];
    #pragma unroll
    for (int q = 0; q < 4; ++q) {
        int n = un + q;
        if (n >= N) break;
        float accH = (q == 0) ? uH0 : (q == 1) ? uH1 : (q == 2) ? uH2 : uH3;
        float accA = (q == 0) ? uA0 : (q == 1) ? uA1 : (q == 2) ? uA2 : uA3;
        float c = cnt[n];
        float rd = 1.0f / fmaxf(c, 1.0f);
        float hv = hin[(size_t)n * H + j];
        float z = hv + accH + rd * accA + bj;
        float s = z;
        for (int o = 32; o > 0; o >>= 1) s += __shfl_xor(s, o);
        float mu = s * (1.0f / H);
        float d = z - mu;
        float v = d * d;
        for (int o = 32; o > 0; o >>= 1) v += __shfl_xor(v, o);
        float var = v * (1.0f / H);
        float r = rsqrtf(var + 1e-5f);
        hout[(size_t)n * H + j] = d * r * gj + betaj;
    }
}

// ---- out = sigmoid(gelu(h @ W1 + b1) @ W2 + b2) ----
__global__ void k_out(const float* __restrict__ h, const float* __restrict__ W1,
                      const float* __restrict__ b1, const float* __restrict__ W2,
                      const float* __restrict__ b2, float* __restrict__ out, int N) {
    __shared__ float w1[H * 32];
    __shared__ float w2[32];
    __shared__ float b1s[32];
    __shared__ float hs[4][H];
    int tid = threadIdx.x;
    for (int i = tid; i < H * 32; i += 256) w1[i] = W1[i];
    if (tid < 32) { w2[tid] = W2[tid]; b1s[tid] = b1[tid]; }
    int ln = tid >> 6, j = tid & 63;
    int n = blockIdx.x * 4 + ln;
    if (n < N) hs[ln][j] = h[n * H + j];
    __syncthreads();
    if (n >= N) return;
    float ge = 0.f;
    if (j < 32) {
        float t = b1s[j];
        #pragma unroll
        for (int k = 0; k < H; ++k) t += hs[ln][k] * w1[k * 32 + j];
        ge = 0.5f * t * (1.0f + erff(t * 0.70710678118654752f)) * w2[j];
    }
    float s = ge;
    for (int o = 32; o > 0; o >>= 1) s += __shfl_xor(s, o);
    if (j == 0) out[n] = 1.0f / (1.0f + expf(-(s + b2[0])));
}

extern "C" void kernel_launch(void* const* d_in, const int* in_sizes, int n_in,
                              void* d_out, int out_size, void* d_ws, size_t ws_size,
                              hipStream_t stream) {
    const float* x    = (const float*)d_in[0];
    const int*   ei   = (const int*)d_in[1];
    const float* Win  = (const float*)d_in[2];
    const float* bin  = (const float*)d_in[3];
    const float* msgW = (const float*)d_in[4];
    const float* msgb = (const float*)d_in[5];
    const float* updW = (const float*)d_in[6];
    const float* updb = (const float*)d_in[7];
    const float* lng  = (const float*)d_in[8];
    const float* lnb  = (const float*)d_in[9];
    const float* W1   = (const float*)d_in[10];
    const float* b1   = (const float*)d_in[11];
    const float* W2   = (const float*)d_in[12];
    const float* b2   = (const float*)d_in[13];

    int N = in_sizes[0] / FIN;
    int E = in_sizes[1] / 2;
    const int* row = ei;
    const int* col = ei + E;

    float* ws   = (float*)d_ws;
    float* cnt  = ws;                        // N
    float* X    = ws + N;                    // N*H
    float* Y    = X + (size_t)N * H;         // N*H
    float* Z    = Y + (size_t)N * H;         // N*H  (aggr)
    int* deg    = (int*)(Z + (size_t)N * H); // N
    int* startv = deg + N;                   // N
    int* cursor = startv + N;                // N
    int* bsum   = cursor + N;                // 512
    int* csr    = bsum + 512;                // E

    int nb = (N + 255) / 256;
    int nb16 = (N + 15) / 16;

    hipMemsetAsync(deg, 0, (size_t)N * sizeof(int), stream);
    k_deg<<<(E + 255) / 256, 256, 0, stream>>>(col, deg, E);
    k_scan1<<<nb, 256, 0, stream>>>(deg, startv, bsum, cnt, N);
    k_scan2<<<1, 512, 0, stream>>>(bsum, nb);
    k_scan3<<<nb, 256, 0, stream>>>(startv, bsum, cursor, N);
    k_fill<<<(E + 255) / 256, 256, 0, stream>>>(row, col, cursor, csr, E);

    k_input<<<nb16, 256, 0, stream>>>(x, Win, bin, X, N);

    // layer 0: h = X -> hout = Y  (A in Y? no: A goes to Y only after swap; here A->Y is
    // wrong since hout=Y. Use: A buffer = Y for l=0 then hout must differ from A.)
    // Rotation: l=0: A->Y, k_upd writes hout->Y AFTER k_aggr consumed A(Y)? k_upd reads
    // only hin(X) and ag(Z), so reusing Y for hout is safe (A dead post-k_aggr).
    k_AB<<<nb16, 256, 0, stream>>>(X, msgW, msgb, cnt, Y, Z, N);
    k_aggr<<<(N + 3) / 4, 256, 0, stream>>>(startv, deg, csr, Y, Z, N);
    k_upd<<<nb16, 256, 0, stream>>>(X, Z, cnt, updW, updb, lng, lnb, Y, N);

    // layer 1: h = Y -> A->X, hout->X (X's old h dead; A dead post-k_aggr)
    k_AB<<<nb16, 256, 0, stream>>>(Y, msgW + 2 * H * H, msgb + H, cnt, X, Z, N);
    k_aggr<<<(N + 3) / 4, 256, 0, stream>>>(startv, deg, csr, X, Z, N);
    k_upd<<<nb16, 256, 0, stream>>>(Y, Z, cnt, updW + 2 * H * H, updb + H, lng + H, lnb + H, X, N);

    k_out<<<(N + 3) / 4, 256, 0, stream>>>(X, W1, b1, W2, b2, (float*)d_out, N);
}

// Round 4
// 558.136 us; speedup vs baseline: 2.1918x; 1.1871x over previous
//
#include <hip/hip_runtime.h>
#include <hip/hip_fp16.h>
#include <math.h>

#define H 64
#define FIN 39

// ---- in-degree, destination-partitioned: group g = blockIdx&7 owns node range g ----
__global__ void k_deg(const int* __restrict__ col, int* __restrict__ deg, int E, int N) {
    int g = blockIdx.x & 7;
    int bg = blockIdx.x >> 3;
    int nbg = gridDim.x >> 3;
    int R = (N + 7) >> 3;
    int lo = g * R;
    int hi = min(N, lo + R);
    for (int e = bg * 256 + threadIdx.x; e < E; e += nbg * 256) {
        int c = col[e];
        if (c >= lo && c < hi) atomicAdd(&deg[c], 1);
    }
}

// ---- scan step 1: per-block exclusive scan of deg; block sums out; also float cnt ----
__global__ void k_scan1(const int* __restrict__ deg, int* __restrict__ startv,
                        int* __restrict__ bsum, float* __restrict__ cnt, int N) {
    __shared__ int lds[256];
    int tid = threadIdx.x;
    int i = blockIdx.x * 256 + tid;
    int v = (i < N) ? deg[i] : 0;
    if (i < N) cnt[i] = (float)v;
    lds[tid] = v;
    __syncthreads();
    int acc = v;
    for (int off = 1; off < 256; off <<= 1) {
        int t = (tid >= off) ? lds[tid - off] : 0;
        __syncthreads();
        acc += t;
        lds[tid] = acc;
        __syncthreads();
    }
    if (i < N) startv[i] = acc - v;
    if (tid == 255) bsum[blockIdx.x] = acc;
}

// ---- scan step 2: exclusive scan of block sums (nb <= 512) ----
__global__ void k_scan2(int* __restrict__ bsum, int nb) {
    __shared__ int lds[512];
    int tid = threadIdx.x;
    int v = (tid < nb) ? bsum[tid] : 0;
    lds[tid] = v;
    __syncthreads();
    int acc = v;
    for (int off = 1; off < 512; off <<= 1) {
        int t = (tid >= off) ? lds[tid - off] : 0;
        __syncthreads();
        acc += t;
        lds[tid] = acc;
        __syncthreads();
    }
    if (tid < nb) bsum[tid] = acc - v;
}

// ---- scan step 3: add block offsets; init cursor ----
__global__ void k_scan3(int* __restrict__ startv, const int* __restrict__ bsum,
                        int* __restrict__ cursor, int N) {
    int i = blockIdx.x * 256 + threadIdx.x;
    if (i < N) {
        int s = startv[i] + bsum[blockIdx.x];
        startv[i] = s;
        cursor[i] = s;
    }
}

// ---- fill CSR, destination-partitioned (csr lines stay XCD-L2-local) ----
__global__ void k_fill(const int* __restrict__ row, const int* __restrict__ col,
                       int* __restrict__ cursor, int* __restrict__ csr, int E, int N) {
    int g = blockIdx.x & 7;
    int bg = blockIdx.x >> 3;
    int nbg = gridDim.x >> 3;
    int R = (N + 7) >> 3;
    int lo = g * R;
    int hi = min(N, lo + R);
    for (int e = bg * 256 + threadIdx.x; e < E; e += nbg * 256) {
        int c = col[e];
        if (c >= lo && c < hi) {
            int pos = atomicAdd(&cursor[c], 1);
            csr[pos] = row[e];
        }
    }
}

// ---- h = x @ W_in + b_in : 16 nodes/block, 4 nodes/thread, scalar x reads ----
__global__ void k_input(const float* __restrict__ x, const float* __restrict__ Win,
                        const float* __restrict__ bin, float* __restrict__ h, int N) {
    __shared__ float w[FIN * H];
    int tid = threadIdx.x;
    for (int i = tid; i < FIN * H; i += 256) w[i] = Win[i];
    __syncthreads();
    int j = tid & 63;
    int nb0 = blockIdx.x * 16 + (tid >> 6) * 4;
    int un = __builtin_amdgcn_readfirstlane(nb0);
    int n0 = min(un, N - 1), n1 = min(un + 1, N - 1), n2 = min(un + 2, N - 1), n3 = min(un + 3, N - 1);
    const float* x0 = x + (size_t)n0 * FIN;
    const float* x1 = x + (size_t)n1 * FIN;
    const float* x2 = x + (size_t)n2 * FIN;
    const float* x3 = x + (size_t)n3 * FIN;
    float a0 = 0.f, a1 = 0.f, a2 = 0.f, a3 = 0.f;
    #pragma unroll
    for (int k = 0; k < FIN; ++k) {
        float wv = w[k * H + j];
        a0 += x0[k] * wv;
        a1 += x1[k] * wv;
        a2 += x2[k] * wv;
        a3 += x3[k] * wv;
    }
    float bj = bin[j];
    if (un     < N) h[(size_t)n0 * H + j] = a0 + bj;
    if (un + 1 < N) h[(size_t)n1 * H + j] = a1 + bj;
    if (un + 2 < N) h[(size_t)n2 * H + j] = a2 + bj;
    if (un + 3 < N) h[(size_t)n3 * H + j] = a3 + bj;
}

// ---- A(half) = h @ W_top ; aggr_init = cnt * (h @ W_bot + msg_b) ----
__global__ void k_AB(const float* __restrict__ h, const float* __restrict__ W,
                     const float* __restrict__ bias, const float* __restrict__ cnt,
                     __half* __restrict__ A, float* __restrict__ aggr, int N) {
    __shared__ float ws[2 * H * H];
    int tid = threadIdx.x;
    {
        const float4* W4 = (const float4*)W;
        float4* s4 = (float4*)ws;
        for (int i = tid; i < 2 * H * H / 4; i += 256) s4[i] = W4[i];
    }
    __syncthreads();
    int j = tid & 63;
    int nb0 = blockIdx.x * 16 + (tid >> 6) * 4;
    int un = __builtin_amdgcn_readfirstlane(nb0);
    int n0 = min(un, N - 1), n1 = min(un + 1, N - 1), n2 = min(un + 2, N - 1), n3 = min(un + 3, N - 1);
    const float* h0 = h + (size_t)n0 * H;
    const float* h1 = h + (size_t)n1 * H;
    const float* h2 = h + (size_t)n2 * H;
    const float* h3 = h + (size_t)n3 * H;
    float a0 = 0.f, a1 = 0.f, a2 = 0.f, a3 = 0.f;
    float b0 = 0.f, b1 = 0.f, b2 = 0.f, b3 = 0.f;
    #pragma unroll 8
    for (int k = 0; k < H; ++k) {
        float w0 = ws[k * H + j];
        float w1 = ws[(H + k) * H + j];
        float s0 = h0[k], s1 = h1[k], s2 = h2[k], s3 = h3[k];
        a0 += s0 * w0; b0 += s0 * w1;
        a1 += s1 * w0; b1 += s1 * w1;
        a2 += s2 * w0; b2 += s2 * w1;
        a3 += s3 * w0; b3 += s3 * w1;
    }
    float bj = bias[j];
    if (un < N) {
        A[(size_t)n0 * H + j] = __float2half(a0);
        aggr[(size_t)n0 * H + j] = cnt[n0] * (b0 + bj);
    }
    if (un + 1 < N) {
        A[(size_t)n1 * H + j] = __float2half(a1);
        aggr[(size_t)n1 * H + j] = cnt[n1] * (b1 + bj);
    }
    if (un + 2 < N) {
        A[(size_t)n2 * H + j] = __float2half(a2);
        aggr[(size_t)n2 * H + j] = cnt[n2] * (b2 + bj);
    }
    if (un + 3 < N) {
        A[(size_t)n3 * H + j] = __float2half(a3);
        aggr[(size_t)n3 * H + j] = cnt[n3] * (b3 + bj);
    }
}

// ---- aggr[n][:] += sum over incoming edges of A[src][:]  (CSR gather, fp16 A) ----
__global__ void k_aggr(const int* __restrict__ startv, const int* __restrict__ deg,
                       const int* __restrict__ csr, const __half* __restrict__ A,
                       float* __restrict__ ag, int N) {
    int tid = threadIdx.x;
    int n = __builtin_amdgcn_readfirstlane(blockIdx.x * 4 + (tid >> 6));
    int j = tid & 63;
    if (n >= N) return;
    int s = startv[n];
    int d = deg[n];
    float acc = ag[(size_t)n * H + j];
    int i = 0;
    for (; i + 8 <= d; i += 8) {
        int r0 = csr[s + i + 0], r1 = csr[s + i + 1], r2 = csr[s + i + 2], r3 = csr[s + i + 3];
        int r4 = csr[s + i + 4], r5 = csr[s + i + 5], r6 = csr[s + i + 6], r7 = csr[s + i + 7];
        float v0 = __half2float(A[(size_t)r0 * H + j]);
        float v1 = __half2float(A[(size_t)r1 * H + j]);
        float v2 = __half2float(A[(size_t)r2 * H + j]);
        float v3 = __half2float(A[(size_t)r3 * H + j]);
        float v4 = __half2float(A[(size_t)r4 * H + j]);
        float v5 = __half2float(A[(size_t)r5 * H + j]);
        float v6 = __half2float(A[(size_t)r6 * H + j]);
        float v7 = __half2float(A[(size_t)r7 * H + j]);
        acc += ((v0 + v1) + (v2 + v3)) + ((v4 + v5) + (v6 + v7));
    }
    for (; i < d; ++i) {
        acc += __half2float(A[(size_t)csr[s + i] * H + j]);
    }
    ag[(size_t)n * H + j] = acc;
}

// ---- upd = [h, aggr/denom] @ upd_W + b ; h' = LN(h+upd)*g+beta ; optionally fused out ----
template<bool DO_OUT>
__global__ void k_upd(const float* __restrict__ hin, const float* __restrict__ ag,
                      const float* __restrict__ cnt, const float* __restrict__ W,
                      const float* __restrict__ bias, const float* __restrict__ g,
                      const float* __restrict__ beta, float* __restrict__ hout,
                      const float* __restrict__ W1, const float* __restrict__ b1,
                      const float* __restrict__ W2, const float* __restrict__ b2,
                      float* __restrict__ out, int N) {
    __shared__ float ws[2 * H * H];
    __shared__ float w1s[DO_OUT ? H * 32 : 1];
    __shared__ float w2s[DO_OUT ? 32 : 1];
    __shared__ float b1s[DO_OUT ? 32 : 1];
    __shared__ float hs[DO_OUT ? 16 * H : 1];
    int tid = threadIdx.x;
    {
        const float4* W4 = (const float4*)W;
        float4* s4 = (float4*)ws;
        for (int i = tid; i < 2 * H * H / 4; i += 256) s4[i] = W4[i];
    }
    if (DO_OUT) {
        for (int i = tid; i < H * 32; i += 256) w1s[i] = W1[i];
        if (tid < 32) { w2s[tid] = W2[tid]; b1s[tid] = b1[tid]; }
    }
    __syncthreads();
    int j = tid & 63;
    int ln = tid >> 6;
    int nb0 = blockIdx.x * 16 + ln * 4;
    int un = __builtin_amdgcn_readfirstlane(nb0);
    int n0 = min(un, N - 1), n1 = min(un + 1, N - 1), n2 = min(un + 2, N - 1), n3 = min(un + 3, N - 1);
    const float* h0 = hin + (size_t)n0 * H;
    const float* h1 = hin + (size_t)n1 * H;
    const float* h2 = hin + (size_t)n2 * H;
    const float* h3 = hin + (size_t)n3 * H;
    const float* g0 = ag + (size_t)n0 * H;
    const float* g1 = ag + (size_t)n1 * H;
    const float* g2 = ag + (size_t)n2 * H;
    const float* g3 = ag + (size_t)n3 * H;
    float uH0 = 0.f, uH1 = 0.f, uH2 = 0.f, uH3 = 0.f;
    float uA0 = 0.f, uA1 = 0.f, uA2 = 0.f, uA3 = 0.f;
    #pragma unroll 4
    for (int k = 0; k < H; ++k) {
        float w0 = ws[k * H + j];
        float w1 = ws[(H + k) * H + j];
        uH0 += h0[k] * w0; uA0 += g0[k] * w1;
        uH1 += h1[k] * w0; uA1 += g1[k] * w1;
        uH2 += h2[k] * w0; uA2 += g2[k] * w1;
        uH3 += h3[k] * w0; uA3 += g3[k] * w1;
    }
    float bj = bias[j], gj = g[j], betaj = beta[j];
    #pragma unroll
    for (int q = 0; q < 4; ++q) {
        int n = un + q;
        if (n < N) {
            float accH = (q == 0) ? uH0 : (q == 1) ? uH1 : (q == 2) ? uH2 : uH3;
            float accA = (q == 0) ? uA0 : (q == 1) ? uA1 : (q == 2) ? uA2 : uA3;
            float rd = 1.0f / fmaxf(cnt[n], 1.0f);
            float hv = hin[(size_t)n * H + j];
            float z = hv + accH + rd * accA + bj;
            float s = z;
            for (int o = 32; o > 0; o >>= 1) s += __shfl_xor(s, o);
            float mu = s * (1.0f / H);
            float d = z - mu;
            float v = d * d;
            for (int o = 32; o > 0; o >>= 1) v += __shfl_xor(v, o);
            float var = v * (1.0f / H);
            float r = rsqrtf(var + 1e-5f);
            float hval = d * r * gj + betaj;
            if (DO_OUT) hs[(ln * 4 + q) * H + j] = hval;
            else        hout[(size_t)n * H + j] = hval;
        }
    }
    if (DO_OUT) {
        __syncthreads();
        int hf = j >> 5, jj = j & 31;
        #pragma unroll
        for (int q = 0; q < 4; ++q) {
            int n = un + q;
            if (n >= N) continue;
            int nbl = ln * 4 + q;
            float t = 0.f;
            #pragma unroll
            for (int kk = 0; kk < 32; ++kk) {
                int k = hf * 32 + kk;
                t += hs[nbl * H + k] * w1s[k * 32 + jj];
            }
            t += __shfl_xor(t, 32);
            float t2 = t + b1s[jj];
            float ge = 0.5f * t2 * (1.0f + erff(t2 * 0.70710678118654752f)) * w2s[jj];
            for (int o = 16; o > 0; o >>= 1) ge += __shfl_xor(ge, o);
            if (j == 0) out[n] = 1.0f / (1.0f + expf(-(ge + b2[0])));
        }
    }
}

extern "C" void kernel_launch(void* const* d_in, const int* in_sizes, int n_in,
                              void* d_out, int out_size, void* d_ws, size_t ws_size,
                              hipStream_t stream) {
    const float* x    = (const float*)d_in[0];
    const int*   ei   = (const int*)d_in[1];
    const float* Win  = (const float*)d_in[2];
    const float* bin  = (const float*)d_in[3];
    const float* msgW = (const float*)d_in[4];
    const float* msgb = (const float*)d_in[5];
    const float* updW = (const float*)d_in[6];
    const float* updb = (const float*)d_in[7];
    const float* lng  = (const float*)d_in[8];
    const float* lnb  = (const float*)d_in[9];
    const float* W1   = (const float*)d_in[10];
    const float* b1   = (const float*)d_in[11];
    const float* W2   = (const float*)d_in[12];
    const float* b2   = (const float*)d_in[13];

    int N = in_sizes[0] / FIN;
    int E = in_sizes[1] / 2;
    const int* row = ei;
    const int* col = ei + E;

    float* wsp  = (float*)d_ws;
    float* cnt  = wsp;                        // N
    float* X    = wsp + N;                    // N*H
    float* Y    = X + (size_t)N * H;          // N*H
    float* Z    = Y + (size_t)N * H;          // N*H  (aggr)
    __half* Ah  = (__half*)(Z + (size_t)N * H);            // N*H halves
    int* deg    = (int*)(Ah + (size_t)N * H); // N
    int* startv = deg + N;                    // N
    int* cursor = startv + N;                 // N
    int* bsum   = cursor + N;                 // 512
    int* csr    = bsum + 512;                 // E

    int nb = (N + 255) / 256;
    int nb16 = (N + 15) / 16;

    hipMemsetAsync(deg, 0, (size_t)N * sizeof(int), stream);
    k_deg<<<1024, 256, 0, stream>>>(col, deg, E, N);
    k_scan1<<<nb, 256, 0, stream>>>(deg, startv, bsum, cnt, N);
    k_scan2<<<1, 512, 0, stream>>>(bsum, nb);
    k_scan3<<<nb, 256, 0, stream>>>(startv, bsum, cursor, N);
    k_fill<<<1024, 256, 0, stream>>>(row, col, cursor, csr, E, N);

    k_input<<<nb16, 256, 0, stream>>>(x, Win, bin, X, N);

    // layer 0: h=X, A->Ah, aggr->Z, hout->Y
    k_AB<<<nb16, 256, 0, stream>>>(X, msgW, msgb, cnt, Ah, Z, N);
    k_aggr<<<(N + 3) / 4, 256, 0, stream>>>(startv, deg, csr, Ah, Z, N);
    k_upd<false><<<nb16, 256, 0, stream>>>(X, Z, cnt, updW, updb, lng, lnb, Y,
                                           nullptr, nullptr, nullptr, nullptr, nullptr, N);

    // layer 1: h=Y, A->Ah, aggr->Z, fused final MLP -> d_out (h2 never hits HBM)
    k_AB<<<nb16, 256, 0, stream>>>(Y, msgW + 2 * H * H, msgb + H, cnt, Ah, Z, N);
    k_aggr<<<(N + 3) / 4, 256, 0, stream>>>(startv, deg, csr, Ah, Z, N);
    k_upd<true><<<nb16, 256, 0, stream>>>(Y, Z, cnt, updW + 2 * H * H, updb + H,
                                          lng + H, lnb + H, X,
                                          W1, b1, W2, b2, (float*)d_out, N);
}

// Round 5
// 493.539 us; speedup vs baseline: 2.4787x; 1.1309x over previous
//
#include <hip/hip_runtime.h>
#include <hip/hip_fp16.h>
#include <math.h>

#define H 64
#define FIN 39

// ---- in-degree, destination-partitioned: group g = blockIdx&7 owns node range g ----
__global__ void k_deg(const int* __restrict__ col, int* __restrict__ deg, int E, int N) {
    int g = blockIdx.x & 7;
    int bg = blockIdx.x >> 3;
    int nbg = gridDim.x >> 3;
    int R = (N + 7) >> 3;
    int lo = g * R;
    int hi = min(N, lo + R);
    for (int e = bg * 256 + threadIdx.x; e < E; e += nbg * 256) {
        int c = col[e];
        if (c >= lo && c < hi) atomicAdd(&deg[c], 1);
    }
}

// ---- scan step 1 ----
__global__ void k_scan1(const int* __restrict__ deg, int* __restrict__ startv,
                        int* __restrict__ bsum, float* __restrict__ cnt, int N) {
    __shared__ int lds[256];
    int tid = threadIdx.x;
    int i = blockIdx.x * 256 + tid;
    int v = (i < N) ? deg[i] : 0;
    if (i < N) cnt[i] = (float)v;
    lds[tid] = v;
    __syncthreads();
    int acc = v;
    for (int off = 1; off < 256; off <<= 1) {
        int t = (tid >= off) ? lds[tid - off] : 0;
        __syncthreads();
        acc += t;
        lds[tid] = acc;
        __syncthreads();
    }
    if (i < N) startv[i] = acc - v;
    if (tid == 255) bsum[blockIdx.x] = acc;
}

// ---- scan step 2 (nb <= 512) ----
__global__ void k_scan2(int* __restrict__ bsum, int nb) {
    __shared__ int lds[512];
    int tid = threadIdx.x;
    int v = (tid < nb) ? bsum[tid] : 0;
    lds[tid] = v;
    __syncthreads();
    int acc = v;
    for (int off = 1; off < 512; off <<= 1) {
        int t = (tid >= off) ? lds[tid - off] : 0;
        __syncthreads();
        acc += t;
        lds[tid] = acc;
        __syncthreads();
    }
    if (tid < nb) bsum[tid] = acc - v;
}

// ---- scan step 3 ----
__global__ void k_scan3(int* __restrict__ startv, const int* __restrict__ bsum,
                        int* __restrict__ cursor, int N) {
    int i = blockIdx.x * 256 + threadIdx.x;
    if (i < N) {
        int s = startv[i] + bsum[blockIdx.x];
        startv[i] = s;
        cursor[i] = s;
    }
}

// ---- fill CSR, destination-partitioned ----
__global__ void k_fill(const int* __restrict__ row, const int* __restrict__ col,
                       int* __restrict__ cursor, int* __restrict__ csr, int E, int N) {
    int g = blockIdx.x & 7;
    int bg = blockIdx.x >> 3;
    int nbg = gridDim.x >> 3;
    int R = (N + 7) >> 3;
    int lo = g * R;
    int hi = min(N, lo + R);
    for (int e = bg * 256 + threadIdx.x; e < E; e += nbg * 256) {
        int c = col[e];
        if (c >= lo && c < hi) {
            int pos = atomicAdd(&cursor[c], 1);
            csr[pos] = row[e];
        }
    }
}

// ---- h = x @ W_in + b_in : 512 thr, 32 nodes/block, 4 nodes/thread ----
__global__ void k_input(const float* __restrict__ x, const float* __restrict__ Win,
                        const float* __restrict__ bin, float* __restrict__ h, int N) {
    __shared__ float w[FIN * H];
    int tid = threadIdx.x;
    for (int i = tid; i < FIN * H; i += 512) w[i] = Win[i];
    __syncthreads();
    int j = tid & 63;
    int nb0 = blockIdx.x * 32 + (tid >> 6) * 4;
    int un = __builtin_amdgcn_readfirstlane(nb0);
    int n0 = min(un, N - 1), n1 = min(un + 1, N - 1), n2 = min(un + 2, N - 1), n3 = min(un + 3, N - 1);
    const float* x0 = x + (size_t)n0 * FIN;
    const float* x1 = x + (size_t)n1 * FIN;
    const float* x2 = x + (size_t)n2 * FIN;
    const float* x3 = x + (size_t)n3 * FIN;
    float a0 = 0.f, a1 = 0.f, a2 = 0.f, a3 = 0.f;
    #pragma unroll
    for (int k = 0; k < FIN; ++k) {
        float wv = w[k * H + j];
        a0 += x0[k] * wv;
        a1 += x1[k] * wv;
        a2 += x2[k] * wv;
        a3 += x3[k] * wv;
    }
    float bj = bin[j];
    if (un     < N) h[(size_t)n0 * H + j] = a0 + bj;
    if (un + 1 < N) h[(size_t)n1 * H + j] = a1 + bj;
    if (un + 2 < N) h[(size_t)n2 * H + j] = a2 + bj;
    if (un + 3 < N) h[(size_t)n3 * H + j] = a3 + bj;
}

// ---- A(half) = h @ W_top ; aggr_init = cnt * (h @ W_bot + msg_b) : 512 thr ----
__global__ void k_AB(const float* __restrict__ h, const float* __restrict__ W,
                     const float* __restrict__ bias, const float* __restrict__ cnt,
                     __half* __restrict__ A, float* __restrict__ aggr, int N) {
    __shared__ float ws[2 * H * H];
    int tid = threadIdx.x;
    {
        const float4* W4 = (const float4*)W;
        float4* s4 = (float4*)ws;
        for (int i = tid; i < 2 * H * H / 4; i += 512) s4[i] = W4[i];
    }
    __syncthreads();
    int j = tid & 63;
    int nb0 = blockIdx.x * 32 + (tid >> 6) * 4;
    int un = __builtin_amdgcn_readfirstlane(nb0);
    int n0 = min(un, N - 1), n1 = min(un + 1, N - 1), n2 = min(un + 2, N - 1), n3 = min(un + 3, N - 1);
    const float* h0 = h + (size_t)n0 * H;
    const float* h1 = h + (size_t)n1 * H;
    const float* h2 = h + (size_t)n2 * H;
    const float* h3 = h + (size_t)n3 * H;
    float a0 = 0.f, a1 = 0.f, a2 = 0.f, a3 = 0.f;
    float b0 = 0.f, b1 = 0.f, b2 = 0.f, b3 = 0.f;
    #pragma unroll 8
    for (int k = 0; k < H; ++k) {
        float w0 = ws[k * H + j];
        float w1 = ws[(H + k) * H + j];
        float s0 = h0[k], s1 = h1[k], s2 = h2[k], s3 = h3[k];
        a0 += s0 * w0; b0 += s0 * w1;
        a1 += s1 * w0; b1 += s1 * w1;
        a2 += s2 * w0; b2 += s2 * w1;
        a3 += s3 * w0; b3 += s3 * w1;
    }
    float bj = bias[j];
    if (un < N) {
        A[(size_t)n0 * H + j] = __float2half(a0);
        aggr[(size_t)n0 * H + j] = cnt[n0] * (b0 + bj);
    }
    if (un + 1 < N) {
        A[(size_t)n1 * H + j] = __float2half(a1);
        aggr[(size_t)n1 * H + j] = cnt[n1] * (b1 + bj);
    }
    if (un + 2 < N) {
        A[(size_t)n2 * H + j] = __float2half(a2);
        aggr[(size_t)n2 * H + j] = cnt[n2] * (b2 + bj);
    }
    if (un + 3 < N) {
        A[(size_t)n3 * H + j] = __float2half(a3);
        aggr[(size_t)n3 * H + j] = cnt[n3] * (b3 + bj);
    }
}

// ---- aggr[n][:] += sum over incoming edges of A[src][:]  (CSR gather, fp16 A) ----
__global__ void k_aggr(const int* __restrict__ startv, const int* __restrict__ deg,
                       const int* __restrict__ csr, const __half* __restrict__ A,
                       float* __restrict__ ag, int N) {
    int tid = threadIdx.x;
    int n = __builtin_amdgcn_readfirstlane(blockIdx.x * 4 + (tid >> 6));
    int j = tid & 63;
    if (n >= N) return;
    int s = startv[n];
    int d = deg[n];
    float acc = ag[(size_t)n * H + j];
    int i = 0;
    for (; i + 8 <= d; i += 8) {
        int r0 = csr[s + i + 0], r1 = csr[s + i + 1], r2 = csr[s + i + 2], r3 = csr[s + i + 3];
        int r4 = csr[s + i + 4], r5 = csr[s + i + 5], r6 = csr[s + i + 6], r7 = csr[s + i + 7];
        float v0 = __half2float(A[(size_t)r0 * H + j]);
        float v1 = __half2float(A[(size_t)r1 * H + j]);
        float v2 = __half2float(A[(size_t)r2 * H + j]);
        float v3 = __half2float(A[(size_t)r3 * H + j]);
        float v4 = __half2float(A[(size_t)r4 * H + j]);
        float v5 = __half2float(A[(size_t)r5 * H + j]);
        float v6 = __half2float(A[(size_t)r6 * H + j]);
        float v7 = __half2float(A[(size_t)r7 * H + j]);
        acc += ((v0 + v1) + (v2 + v3)) + ((v4 + v5) + (v6 + v7));
    }
    for (; i < d; ++i) {
        acc += __half2float(A[(size_t)csr[s + i] * H + j]);
    }
    ag[(size_t)n * H + j] = acc;
}

// ---- upd + LN (+ fused out MLP) : 512 thr, 32 nodes/block, 4 nodes/thread ----
template<bool DO_OUT>
__global__ void k_upd(const float* __restrict__ hin, const float* __restrict__ ag,
                      const float* __restrict__ cnt, const float* __restrict__ W,
                      const float* __restrict__ bias, const float* __restrict__ g,
                      const float* __restrict__ beta, float* __restrict__ hout,
                      const float* __restrict__ W1, const float* __restrict__ b1,
                      const float* __restrict__ W2, const float* __restrict__ b2,
                      float* __restrict__ out, int N) {
    __shared__ float ws[2 * H * H];
    __shared__ float w1s[DO_OUT ? H * 32 : 1];
    __shared__ float w2s[DO_OUT ? 32 : 1];
    __shared__ float b1s[DO_OUT ? 32 : 1];
    __shared__ float hs[DO_OUT ? 32 * H : 1];
    int tid = threadIdx.x;
    {
        const float4* W4 = (const float4*)W;
        float4* s4 = (float4*)ws;
        for (int i = tid; i < 2 * H * H / 4; i += 512) s4[i] = W4[i];
    }
    if (DO_OUT) {
        for (int i = tid; i < H * 32; i += 512) w1s[i] = W1[i];
        if (tid < 32) { w2s[tid] = W2[tid]; b1s[tid] = b1[tid]; }
    }
    __syncthreads();
    int j = tid & 63;
    int ln = tid >> 6;
    int nb0 = blockIdx.x * 32 + ln * 4;
    int un = __builtin_amdgcn_readfirstlane(nb0);
    int n0 = min(un, N - 1), n1 = min(un + 1, N - 1), n2 = min(un + 2, N - 1), n3 = min(un + 3, N - 1);
    const float* h0 = hin + (size_t)n0 * H;
    const float* h1 = hin + (size_t)n1 * H;
    const float* h2 = hin + (size_t)n2 * H;
    const float* h3 = hin + (size_t)n3 * H;
    const float* g0 = ag + (size_t)n0 * H;
    const float* g1 = ag + (size_t)n1 * H;
    const float* g2 = ag + (size_t)n2 * H;
    const float* g3 = ag + (size_t)n3 * H;
    float uH0 = 0.f, uH1 = 0.f, uH2 = 0.f, uH3 = 0.f;
    float uA0 = 0.f, uA1 = 0.f, uA2 = 0.f, uA3 = 0.f;
    #pragma unroll 4
    for (int k = 0; k < H; ++k) {
        float w0 = ws[k * H + j];
        float w1 = ws[(H + k) * H + j];
        uH0 += h0[k] * w0; uA0 += g0[k] * w1;
        uH1 += h1[k] * w0; uA1 += g1[k] * w1;
        uH2 += h2[k] * w0; uA2 += g2[k] * w1;
        uH3 += h3[k] * w0; uA3 += g3[k] * w1;
    }
    float bj = bias[j], gj = g[j], betaj = beta[j];
    #pragma unroll
    for (int q = 0; q < 4; ++q) {
        int n = un + q;
        if (n < N) {
            float accH = (q == 0) ? uH0 : (q == 1) ? uH1 : (q == 2) ? uH2 : uH3;
            float accA = (q == 0) ? uA0 : (q == 1) ? uA1 : (q == 2) ? uA2 : uA3;
            float rd = 1.0f / fmaxf(cnt[n], 1.0f);
            float hv = hin[(size_t)n * H + j];
            float z = hv + accH + rd * accA + bj;
            float s = z;
            for (int o = 32; o > 0; o >>= 1) s += __shfl_xor(s, o);
            float mu = s * (1.0f / H);
            float d = z - mu;
            float v = d * d;
            for (int o = 32; o > 0; o >>= 1) v += __shfl_xor(v, o);
            float var = v * (1.0f / H);
            float r = rsqrtf(var + 1e-5f);
            float hval = d * r * gj + betaj;
            if (DO_OUT) hs[(ln * 4 + q) * H + j] = hval;
            else        hout[(size_t)n * H + j] = hval;
        }
    }
    if (DO_OUT) {
        __syncthreads();
        int hf = j >> 5, jj = j & 31;
        #pragma unroll
        for (int q = 0; q < 4; ++q) {
            int n = un + q;
            if (n >= N) continue;
            int nbl = ln * 4 + q;
            float t = 0.f;
            #pragma unroll
            for (int kk = 0; kk < 32; ++kk) {
                int k = hf * 32 + kk;
                t += hs[nbl * H + k] * w1s[k * 32 + jj];
            }
            t += __shfl_xor(t, 32);
            float t2 = t + b1s[jj];
            float ge = 0.5f * t2 * (1.0f + erff(t2 * 0.70710678118654752f)) * w2s[jj];
            for (int o = 16; o > 0; o >>= 1) ge += __shfl_xor(ge, o);
            if (j == 0) out[n] = 1.0f / (1.0f + expf(-(ge + b2[0])));
        }
    }
}

extern "C" void kernel_launch(void* const* d_in, const int* in_sizes, int n_in,
                              void* d_out, int out_size, void* d_ws, size_t ws_size,
                              hipStream_t stream) {
    const float* x    = (const float*)d_in[0];
    const int*   ei   = (const int*)d_in[1];
    const float* Win  = (const float*)d_in[2];
    const float* bin  = (const float*)d_in[3];
    const float* msgW = (const float*)d_in[4];
    const float* msgb = (const float*)d_in[5];
    const float* updW = (const float*)d_in[6];
    const float* updb = (const float*)d_in[7];
    const float* lng  = (const float*)d_in[8];
    const float* lnb  = (const float*)d_in[9];
    const float* W1   = (const float*)d_in[10];
    const float* b1   = (const float*)d_in[11];
    const float* W2   = (const float*)d_in[12];
    const float* b2   = (const float*)d_in[13];

    int N = in_sizes[0] / FIN;
    int E = in_sizes[1] / 2;
    const int* row = ei;
    const int* col = ei + E;

    float* wsp  = (float*)d_ws;
    float* cnt  = wsp;                        // N
    float* X    = wsp + N;                    // N*H
    float* Y    = X + (size_t)N * H;          // N*H
    float* Z    = Y + (size_t)N * H;          // N*H  (aggr)
    __half* Ah  = (__half*)(Z + (size_t)N * H);            // N*H halves
    int* deg    = (int*)(Ah + (size_t)N * H); // N
    int* startv = deg + N;                    // N
    int* cursor = startv + N;                 // N
    int* bsum   = cursor + N;                 // 512
    int* csr    = bsum + 512;                 // E

    int nb = (N + 255) / 256;
    int nb32 = (N + 31) / 32;

    hipMemsetAsync(deg, 0, (size_t)N * sizeof(int), stream);
    k_deg<<<1024, 256, 0, stream>>>(col, deg, E, N);
    k_scan1<<<nb, 256, 0, stream>>>(deg, startv, bsum, cnt, N);
    k_scan2<<<1, 512, 0, stream>>>(bsum, nb);
    k_scan3<<<nb, 256, 0, stream>>>(startv, bsum, cursor, N);
    k_fill<<<1024, 256, 0, stream>>>(row, col, cursor, csr, E, N);

    k_input<<<nb32, 512, 0, stream>>>(x, Win, bin, X, N);

    // layer 0: h=X, A->Ah, aggr->Z, hout->Y
    k_AB<<<nb32, 512, 0, stream>>>(X, msgW, msgb, cnt, Ah, Z, N);
    k_aggr<<<(N + 3) / 4, 256, 0, stream>>>(startv, deg, csr, Ah, Z, N);
    k_upd<false><<<nb32, 512, 0, stream>>>(X, Z, cnt, updW, updb, lng, lnb, Y,
                                           nullptr, nullptr, nullptr, nullptr, nullptr, N);

    // layer 1: h=Y, A->Ah, aggr->Z, fused final MLP -> d_out
    k_AB<<<nb32, 512, 0, stream>>>(Y, msgW + 2 * H * H, msgb + H, cnt, Ah, Z, N);
    k_aggr<<<(N + 3) / 4, 256, 0, stream>>>(startv, deg, csr, Ah, Z, N);
    k_upd<true><<<nb32, 512, 0, stream>>>(Y, Z, cnt, updW + 2 * H * H, updb + H,
                                          lng + H, lnb + H, X,
                                          W1, b1, W2, b2, (float*)d_out, N);
}